// Round 1
// baseline (1055.926 us; speedup 1.0000x reference)
//
#include <hip/hip_runtime.h>
#include <stdint.h>

#define T 8192
#define H 1024
#define F 4096
#define E 8
#define K_TOP 2
#define TK (T * K_TOP)

#define BM 128
#define BN 128
#define BK 32

typedef unsigned short u16;
typedef __bf16 bf16x8 __attribute__((ext_vector_type(8)));
typedef float f32x4 __attribute__((ext_vector_type(4)));

// ---------- helpers ----------
__device__ __forceinline__ u16 f2bf(float f) {
    union { float f; uint32_t u; } v; v.f = f;
    uint32_t r = v.u + 0x7FFFu + ((v.u >> 16) & 1u);   // RNE
    return (u16)(r >> 16);
}

__device__ __forceinline__ void async_cp16(const u16* g, u16* l) {
    __builtin_amdgcn_global_load_lds(
        (const __attribute__((address_space(1))) void*)g,
        (__attribute__((address_space(3))) void*)l, 16, 0, 0);
}

// ---------- routing ----------
__global__ __launch_bounds__(256) void count_kernel(const int* __restrict__ ce,
                                                    int* __restrict__ counts) {
    int p = blockIdx.x * 256 + threadIdx.x;
    if (p < TK) atomicAdd(&counts[ce[p]], 1);
}

__global__ void scan_kernel(const int* __restrict__ counts, int* __restrict__ offsets) {
    if (threadIdx.x == 0) {
        int s = 0;
        for (int e = 0; e < E; e++) { offsets[e] = s; s += counts[e]; }
    }
}

__global__ __launch_bounds__(256) void fill_kernel(const int* __restrict__ ce,
                                                   const float* __restrict__ gate,
                                                   const int* __restrict__ offsets,
                                                   int* __restrict__ fill,
                                                   int* __restrict__ tokbuf,
                                                   float* __restrict__ gwbuf) {
    int p = blockIdx.x * 256 + threadIdx.x;
    if (p < TK) {
        int e = ce[p];
        int pos = offsets[e] + atomicAdd(&fill[e], 1);
        tokbuf[pos] = p >> 1;          // t = p / K_TOP (K_TOP==2)
        gwbuf[pos] = gate[p];
    }
}

// ---------- fp32 -> bf16 convert (x) ----------
__global__ __launch_bounds__(256) void cvt_bf16(const float* __restrict__ in,
                                                u16* __restrict__ out, int n) {
    int i = (blockIdx.x * 256 + threadIdx.x) * 4;
    if (i < n) {
        float4 v = *(const float4*)(in + i);
        ushort4 o;
        o.x = f2bf(v.x); o.y = f2bf(v.y); o.z = f2bf(v.z); o.w = f2bf(v.w);
        *(ushort4*)(out + i) = o;
    }
}

// ---------- fp32 (R x C) -> bf16 transposed (C x R), per expert (blockIdx.z) ----------
// Vectorized: float4 global loads (16B/lane), ushort4 global stores (8B/lane).
// LDS tile [64][66]: 66-u16 row stride keeps both access phases <=2-way (free).
__global__ __launch_bounds__(256) void transpose_cvt(const float* __restrict__ in,
                                                     u16* __restrict__ out,
                                                     int R, int C) {
    __shared__ u16 tile[64][66];
    int e = blockIdx.z;
    const float* src = in + (size_t)e * R * C;
    u16* dst = out + (size_t)e * R * C;
    int c0 = blockIdx.x * 64, r0 = blockIdx.y * 64;
    int q = threadIdx.x & 15;      // 4-elem chunk index
    int s = threadIdx.x >> 4;      // 0..15
#pragma unroll
    for (int p = 0; p < 4; p++) {
        int row = s + p * 16;
        float4 v = *(const float4*)(src + (size_t)(r0 + row) * C + c0 + q * 4);
        tile[row][q * 4 + 0] = f2bf(v.x);
        tile[row][q * 4 + 1] = f2bf(v.y);
        tile[row][q * 4 + 2] = f2bf(v.z);
        tile[row][q * 4 + 3] = f2bf(v.w);
    }
    __syncthreads();
#pragma unroll
    for (int p = 0; p < 4; p++) {
        int c = s + p * 16;        // orig col = output row
        ushort4 o;
        o.x = tile[q * 4 + 0][c];
        o.y = tile[q * 4 + 1][c];
        o.z = tile[q * 4 + 2][c];
        o.w = tile[q * 4 + 3][c];
        *(ushort4*)(dst + (size_t)(c0 + c) * R + r0 + q * 4) = o;
    }
}

// ---------- fc1: h[slot] = gelu(x[tok[slot]] @ w1[e])  (bf16 out) ----------
// Double-buffered LDS (T3 minimum 2-phase): issue next K-step's global_load_lds
// BEFORE computing current step; ONE __syncthreads (vmcnt drain) per K-step.
__global__ __launch_bounds__(256, 2) void fc1_kernel(const u16* __restrict__ xb,   // T x H
                                                     const u16* __restrict__ w1t,  // E x F x H
                                                     const int* __restrict__ tokbuf,
                                                     const int* __restrict__ counts,
                                                     const int* __restrict__ offsets,
                                                     u16* __restrict__ hbuf) {     // TK x F
    __shared__ __align__(16) u16 As[2][BM * BK];
    __shared__ __align__(16) u16 Bs[2][BM * BK];

    const int e = blockIdx.z;
    const int cnt = counts[e];
    const int off = offsets[e];
    const int nt = blockIdx.x;             // F / BN tiles
    const int tid = threadIdx.x;
    const int lane = tid & 63;
    const int wave = tid >> 6;
    const int wr = wave >> 1, wc = wave & 1;
    const int quad = lane >> 4, l16 = lane & 15;
    const int r0 = tid >> 2;               // staging row (0..63)
    const int kc = tid & 3;                // 16B chunk within 64B row

    for (int rt = blockIdx.y; rt * BM < cnt; rt += gridDim.y) {
        int m0 = rt * BM + r0, m1 = m0 + 64;
        int t0 = tokbuf[off + (m0 < cnt ? m0 : cnt - 1)];
        int t1 = tokbuf[off + (m1 < cnt ? m1 : cnt - 1)];
        const u16* a0 = xb + (size_t)t0 * H + kc * 8;
        const u16* a1 = xb + (size_t)t1 * H + kc * 8;
        const u16* b0 = w1t + ((size_t)e * F + nt * BN + r0) * H + kc * 8;
        const u16* b1 = b0 + (size_t)64 * H;

        f32x4 acc[4][4];
#pragma unroll
        for (int i = 0; i < 4; i++)
#pragma unroll
            for (int j = 0; j < 4; j++) acc[i][j] = (f32x4)0.f;

        // prologue: stage k0=0 into buffer 0
        async_cp16(a0, &As[0][tid * 8]);
        async_cp16(a1, &As[0][(tid + 256) * 8]);
        async_cp16(b0, &Bs[0][tid * 8]);
        async_cp16(b1, &Bs[0][(tid + 256) * 8]);
        __syncthreads();

        int cur = 0;
        for (int k0 = 0; k0 < H; k0 += BK) {
            int kn = k0 + BK;
            if (kn < H) {                  // issue next-step stage (overlaps MFMA)
                async_cp16(a0 + kn, &As[cur ^ 1][tid * 8]);
                async_cp16(a1 + kn, &As[cur ^ 1][(tid + 256) * 8]);
                async_cp16(b0 + kn, &Bs[cur ^ 1][tid * 8]);
                async_cp16(b1 + kn, &Bs[cur ^ 1][(tid + 256) * 8]);
            }

            bf16x8 af[4], bfv[4];
#pragma unroll
            for (int mi = 0; mi < 4; mi++)
                af[mi] = *(const bf16x8*)&As[cur][(wr * 64 + mi * 16 + l16) * BK + quad * 8];
#pragma unroll
            for (int ni = 0; ni < 4; ni++)
                bfv[ni] = *(const bf16x8*)&Bs[cur][(wc * 64 + ni * 16 + l16) * BK + quad * 8];
#pragma unroll
            for (int mi = 0; mi < 4; mi++)
#pragma unroll
                for (int ni = 0; ni < 4; ni++)
                    acc[mi][ni] = __builtin_amdgcn_mfma_f32_16x16x32_bf16(
                        af[mi], bfv[ni], acc[mi][ni], 0, 0, 0);

            __syncthreads();               // drains vmcnt(0): next buffer ready
            cur ^= 1;
        }

        // epilogue: gelu(tanh approx) -> bf16 h
#pragma unroll
        for (int mi = 0; mi < 4; mi++) {
#pragma unroll
            for (int r = 0; r < 4; r++) {
                int m = rt * BM + wr * 64 + mi * 16 + quad * 4 + r;
                if (m < cnt) {
                    size_t rowbase = (size_t)(off + m) * F;
#pragma unroll
                    for (int ni = 0; ni < 4; ni++) {
                        float v = acc[mi][ni][r];
                        float u = 0.7978845608028654f * (v + 0.044715f * v * v * v);
                        float g = v / (1.f + __expf(-2.f * u));   // v * sigmoid(2u)
                        int fcol = nt * BN + wc * 64 + ni * 16 + l16;
                        hbuf[rowbase + fcol] = f2bf(g);
                    }
                }
            }
        }
    }
}

// ---------- fc2: out[tok[slot]] += gw[slot] * (h[slot] @ w2[e]) ----------
__global__ __launch_bounds__(256, 2) void fc2_kernel(const u16* __restrict__ hbuf,  // TK x F
                                                     const u16* __restrict__ w2t,   // E x H x F
                                                     const int* __restrict__ tokbuf,
                                                     const float* __restrict__ gwbuf,
                                                     const int* __restrict__ counts,
                                                     const int* __restrict__ offsets,
                                                     float* __restrict__ out) {     // T x H
    __shared__ __align__(16) u16 As[2][BM * BK];
    __shared__ __align__(16) u16 Bs[2][BM * BK];

    const int e = blockIdx.z;
    const int cnt = counts[e];
    const int off = offsets[e];
    const int nt = blockIdx.x;             // H / BN tiles
    const int tid = threadIdx.x;
    const int lane = tid & 63;
    const int wave = tid >> 6;
    const int wr = wave >> 1, wc = wave & 1;
    const int quad = lane >> 4, l16 = lane & 15;
    const int r0 = tid >> 2;
    const int kc = tid & 3;

    for (int rt = blockIdx.y; rt * BM < cnt; rt += gridDim.y) {
        int m0 = rt * BM + r0, m1 = m0 + 64;
        int s0 = off + (m0 < cnt ? m0 : cnt - 1);
        int s1 = off + (m1 < cnt ? m1 : cnt - 1);
        const u16* a0 = hbuf + (size_t)s0 * F + kc * 8;
        const u16* a1 = hbuf + (size_t)s1 * F + kc * 8;
        const u16* b0 = w2t + ((size_t)e * H + nt * BN + r0) * F + kc * 8;
        const u16* b1 = b0 + (size_t)64 * F;

        f32x4 acc[4][4];
#pragma unroll
        for (int i = 0; i < 4; i++)
#pragma unroll
            for (int j = 0; j < 4; j++) acc[i][j] = (f32x4)0.f;

        // prologue: stage k0=0 into buffer 0
        async_cp16(a0, &As[0][tid * 8]);
        async_cp16(a1, &As[0][(tid + 256) * 8]);
        async_cp16(b0, &Bs[0][tid * 8]);
        async_cp16(b1, &Bs[0][(tid + 256) * 8]);
        __syncthreads();

        int cur = 0;
        for (int k0 = 0; k0 < F; k0 += BK) {
            int kn = k0 + BK;
            if (kn < F) {                  // issue next-step stage (overlaps MFMA)
                async_cp16(a0 + kn, &As[cur ^ 1][tid * 8]);
                async_cp16(a1 + kn, &As[cur ^ 1][(tid + 256) * 8]);
                async_cp16(b0 + kn, &Bs[cur ^ 1][tid * 8]);
                async_cp16(b1 + kn, &Bs[cur ^ 1][(tid + 256) * 8]);
            }

            bf16x8 af[4], bfv[4];
#pragma unroll
            for (int mi = 0; mi < 4; mi++)
                af[mi] = *(const bf16x8*)&As[cur][(wr * 64 + mi * 16 + l16) * BK + quad * 8];
#pragma unroll
            for (int ni = 0; ni < 4; ni++)
                bfv[ni] = *(const bf16x8*)&Bs[cur][(wc * 64 + ni * 16 + l16) * BK + quad * 8];
#pragma unroll
            for (int mi = 0; mi < 4; mi++)
#pragma unroll
                for (int ni = 0; ni < 4; ni++)
                    acc[mi][ni] = __builtin_amdgcn_mfma_f32_16x16x32_bf16(
                        af[mi], bfv[ni], acc[mi][ni], 0, 0, 0);

            __syncthreads();               // drains vmcnt(0): next buffer ready
            cur ^= 1;
        }

#pragma unroll
        for (int mi = 0; mi < 4; mi++) {
#pragma unroll
            for (int r = 0; r < 4; r++) {
                int m = rt * BM + wr * 64 + mi * 16 + quad * 4 + r;
                if (m < cnt) {
                    int t = tokbuf[off + m];
                    float g = gwbuf[off + m];
                    size_t obase = (size_t)t * H;
#pragma unroll
                    for (int ni = 0; ni < 4; ni++) {
                        int col = nt * BN + wc * 64 + ni * 16 + l16;
                        atomicAdd(&out[obase + col], g * acc[mi][ni][r]);
                    }
                }
            }
        }
    }
}

// ---------- launch ----------
extern "C" void kernel_launch(void* const* d_in, const int* in_sizes, int n_in,
                              void* d_out, int out_size, void* d_ws, size_t ws_size,
                              hipStream_t stream) {
    const float* x    = (const float*)d_in[0];   // S,B,H fp32
    const float* gate = (const float*)d_in[1];   // T,K
    const int*   ce   = (const int*)d_in[2];     // T,K
    const float* w1   = (const float*)d_in[3];   // E,H,F
    const float* w2   = (const float*)d_in[4];   // E,F,H
    float* out = (float*)d_out;
    char* ws = (char*)d_ws;

    // workspace layout
    int*   counts  = (int*)(ws + 0);                 // 8
    int*   fill    = (int*)(ws + 32);                // 8
    int*   offsets = (int*)(ws + 64);                // 8
    int*   tokbuf  = (int*)(ws + 256);               // TK
    float* gwbuf   = (float*)(ws + 256 + TK * 4);    // TK
    size_t o = 256 + (size_t)TK * 8;
    u16* xb  = (u16*)(ws + o);  o += (size_t)T * H * 2;       // 16.8 MB
    u16* w1t = (u16*)(ws + o);  o += (size_t)E * F * H * 2;   // 67 MB  (E,F,H)
    u16* w2t = (u16*)(ws + o);  o += (size_t)E * H * F * 2;   // 67 MB  (E,H,F)
    u16* hbuf = (u16*)(ws + o);                                // TK x F bf16, 134 MB

    hipMemsetAsync(ws, 0, 256, stream);                        // counts + fill
    hipMemsetAsync(d_out, 0, (size_t)T * H * sizeof(float), stream);

    count_kernel<<<TK / 256, 256, 0, stream>>>(ce, counts);
    scan_kernel<<<1, 64, 0, stream>>>(counts, offsets);
    fill_kernel<<<TK / 256, 256, 0, stream>>>(ce, gate, offsets, fill, tokbuf, gwbuf);

    cvt_bf16<<<(T * H) / (256 * 4), 256, 0, stream>>>(x, xb, T * H);
    transpose_cvt<<<dim3(F / 64, H / 64, E), 256, 0, stream>>>(w1, w1t, H, F);  // (H,F)->(F,H)
    transpose_cvt<<<dim3(H / 64, F / 64, E), 256, 0, stream>>>(w2, w2t, F, H);  // (F,H)->(H,F)

    fc1_kernel<<<dim3(F / BN, 32, E), 256, 0, stream>>>(xb, w1t, tokbuf, counts, offsets, hbuf);
    fc2_kernel<<<dim3(H / BN, 32, E), 256, 0, stream>>>(hbuf, w2t, tokbuf, gwbuf, counts, offsets, out);
}

// Round 2
// 1048.949 us; speedup vs baseline: 1.0067x; 1.0067x over previous
//
#include <hip/hip_runtime.h>
#include <stdint.h>

#define T 8192
#define H 1024
#define F 4096
#define E 8
#define K_TOP 2
#define TK (T * K_TOP)

#define BM 128
#define BN 128
#define BK 32
#define BUFSZ (BM * BK)   // u16 elements per LDS buffer (8 KB)

typedef unsigned short u16;
typedef __bf16 bf16x8 __attribute__((ext_vector_type(8)));
typedef float f32x4 __attribute__((ext_vector_type(4)));

// ---------- helpers ----------
__device__ __forceinline__ u16 f2bf(float f) {
    union { float f; uint32_t u; } v; v.f = f;
    uint32_t r = v.u + 0x7FFFu + ((v.u >> 16) & 1u);   // RNE
    return (u16)(r >> 16);
}

__device__ __forceinline__ void async_cp16(const u16* g, u16* l) {
    __builtin_amdgcn_global_load_lds(
        (const __attribute__((address_space(1))) void*)g,
        (__attribute__((address_space(3))) void*)l, 16, 0, 0);
}

#define CFENCE asm volatile("" ::: "memory")

// ---------- routing ----------
__global__ __launch_bounds__(256) void count_kernel(const int* __restrict__ ce,
                                                    int* __restrict__ counts) {
    int p = blockIdx.x * 256 + threadIdx.x;
    if (p < TK) atomicAdd(&counts[ce[p]], 1);
}

__global__ void scan_kernel(const int* __restrict__ counts, int* __restrict__ offsets) {
    if (threadIdx.x == 0) {
        int s = 0;
        for (int e = 0; e < E; e++) { offsets[e] = s; s += counts[e]; }
    }
}

__global__ __launch_bounds__(256) void fill_kernel(const int* __restrict__ ce,
                                                   const float* __restrict__ gate,
                                                   const int* __restrict__ offsets,
                                                   int* __restrict__ fill,
                                                   int* __restrict__ tokbuf,
                                                   float* __restrict__ gwbuf) {
    int p = blockIdx.x * 256 + threadIdx.x;
    if (p < TK) {
        int e = ce[p];
        int pos = offsets[e] + atomicAdd(&fill[e], 1);
        tokbuf[pos] = p >> 1;          // t = p / K_TOP (K_TOP==2)
        gwbuf[pos] = gate[p];
    }
}

// ---------- fp32 -> bf16 convert (x) ----------
__global__ __launch_bounds__(256) void cvt_bf16(const float* __restrict__ in,
                                                u16* __restrict__ out, int n) {
    int i = (blockIdx.x * 256 + threadIdx.x) * 4;
    if (i < n) {
        float4 v = *(const float4*)(in + i);
        ushort4 o;
        o.x = f2bf(v.x); o.y = f2bf(v.y); o.z = f2bf(v.z); o.w = f2bf(v.w);
        *(ushort4*)(out + i) = o;
    }
}

// ---------- fp32 (R x C) -> bf16 transposed (C x R), per expert (blockIdx.z) ----------
__global__ __launch_bounds__(256) void transpose_cvt(const float* __restrict__ in,
                                                     u16* __restrict__ out,
                                                     int R, int C) {
    __shared__ u16 tile[64][66];
    int e = blockIdx.z;
    const float* src = in + (size_t)e * R * C;
    u16* dst = out + (size_t)e * R * C;
    int c0 = blockIdx.x * 64, r0 = blockIdx.y * 64;
    int q = threadIdx.x & 15;      // 4-elem chunk index
    int s = threadIdx.x >> 4;      // 0..15
#pragma unroll
    for (int p = 0; p < 4; p++) {
        int row = s + p * 16;
        float4 v = *(const float4*)(src + (size_t)(r0 + row) * C + c0 + q * 4);
        tile[row][q * 4 + 0] = f2bf(v.x);
        tile[row][q * 4 + 1] = f2bf(v.y);
        tile[row][q * 4 + 2] = f2bf(v.z);
        tile[row][q * 4 + 3] = f2bf(v.w);
    }
    __syncthreads();
#pragma unroll
    for (int p = 0; p < 4; p++) {
        int c = s + p * 16;        // orig col = output row
        ushort4 o;
        o.x = tile[q * 4 + 0][c];
        o.y = tile[q * 4 + 1][c];
        o.z = tile[q * 4 + 2][c];
        o.w = tile[q * 4 + 3][c];
        *(ushort4*)(dst + (size_t)(c0 + c) * R + r0 + q * 4) = o;
    }
}

// stage tile into LDS buffer s (byte-linear, matches round-0 layout)
#define STAGE(s, ks)                                                        \
    do {                                                                    \
        const int _o = (s) * BUFSZ;                                         \
        async_cp16(a0 + (ks), (u16*)As + _o + tid * 8);                     \
        async_cp16(a1 + (ks), (u16*)As + _o + (tid + 256) * 8);             \
        async_cp16(b0 + (ks), (u16*)Bs + _o + tid * 8);                     \
        async_cp16(b1 + (ks), (u16*)Bs + _o + (tid + 256) * 8);             \
    } while (0)

// ---------- fc1: h[slot] = gelu(x[tok[slot]] @ w1[e])  (bf16 out) ----------
// 3-stage pipeline: triple-buffered LDS, counted vmcnt (never 0 in steady
// state), raw s_barrier (no vmcnt(0) drain).  48 KB LDS -> 3 blocks/CU.
__global__ __launch_bounds__(256, 2) void fc1_kernel(const u16* __restrict__ xb,   // T x H
                                                     const u16* __restrict__ w1t,  // E x F x H
                                                     const int* __restrict__ tokbuf,
                                                     const int* __restrict__ counts,
                                                     const int* __restrict__ offsets,
                                                     u16* __restrict__ hbuf) {     // TK x F
    __shared__ __align__(16) u16 As[3 * BUFSZ];
    __shared__ __align__(16) u16 Bs[3 * BUFSZ];

    const int e = blockIdx.z;
    const int cnt = counts[e];
    const int off = offsets[e];
    // XCD-chunked swizzle: grid (32,16); 512 blocks/expert, 64/XCD.
    // XCD c gets rt-band {2c,2c+1} x all nt  -> A-panels fetched once chip-wide.
    const int fhw = blockIdx.x + 32 * blockIdx.y;
    const int f   = (fhw & 7) * 64 + (fhw >> 3);
    const int nt  = f & 31;              // F/BN tile
    const int by  = f >> 5;              // M-tile start (0..15)

    const int tid = threadIdx.x;
    const int lane = tid & 63;
    const int wave = tid >> 6;
    const int wr = wave >> 1, wc = wave & 1;
    const int quad = lane >> 4, l16 = lane & 15;
    const int r0 = tid >> 2;               // staging row (0..63)
    const int kc = tid & 3;                // 16B chunk within 64B row

    const int NS = H / BK;                 // 32 K-steps

    for (int rt = by; rt * BM < cnt; rt += 16) {
        int m0 = rt * BM + r0, m1 = m0 + 64;
        int t0 = tokbuf[off + (m0 < cnt ? m0 : cnt - 1)];
        int t1 = tokbuf[off + (m1 < cnt ? m1 : cnt - 1)];
        const u16* a0 = xb + (size_t)t0 * H + kc * 8;
        const u16* a1 = xb + (size_t)t1 * H + kc * 8;
        const u16* b0 = w1t + ((size_t)e * F + nt * BN + r0) * H + kc * 8;
        const u16* b1 = b0 + (size_t)64 * H;

        f32x4 acc[4][4];
#pragma unroll
        for (int i = 0; i < 4; i++)
#pragma unroll
            for (int j = 0; j < 4; j++) acc[i][j] = (f32x4)0.f;

        __builtin_amdgcn_s_barrier();      // prev tile's LDS reads all landed
        CFENCE;
        STAGE(0, 0);
        STAGE(1, BK);

        int cur = 0;
        for (int i = 0; i < NS; ++i) {
            __builtin_amdgcn_s_barrier();  // reads of tile i-1 done -> safe to overwrite
            CFENCE;
            if (i < NS - 2) {
                int s2 = (cur == 0) ? 2 : cur - 1;   // (cur+2)%3
                STAGE(s2, (i + 2) * BK);
                asm volatile("s_waitcnt vmcnt(8)" ::: "memory");  // tile i landed
            } else if (i == NS - 2) {
                asm volatile("s_waitcnt vmcnt(4)" ::: "memory");
            } else {
                asm volatile("s_waitcnt vmcnt(0)" ::: "memory");
            }
            __builtin_amdgcn_s_barrier();  // all waves: tile i staged
            CFENCE;

            const u16* Ab = As + cur * BUFSZ;
            const u16* Bb = Bs + cur * BUFSZ;
            bf16x8 af[4], bfv[4];
#pragma unroll
            for (int mi = 0; mi < 4; mi++)
                af[mi] = *(const bf16x8*)&Ab[(wr * 64 + mi * 16 + l16) * BK + quad * 8];
#pragma unroll
            for (int ni = 0; ni < 4; ni++)
                bfv[ni] = *(const bf16x8*)&Bb[(wc * 64 + ni * 16 + l16) * BK + quad * 8];
#pragma unroll
            for (int mi = 0; mi < 4; mi++)
#pragma unroll
                for (int ni = 0; ni < 4; ni++)
                    acc[mi][ni] = __builtin_amdgcn_mfma_f32_16x16x32_bf16(
                        af[mi], bfv[ni], acc[mi][ni], 0, 0, 0);

            cur = (cur == 2) ? 0 : cur + 1;
        }

        // epilogue: gelu(tanh approx) -> bf16 h
#pragma unroll
        for (int mi = 0; mi < 4; mi++) {
#pragma unroll
            for (int r = 0; r < 4; r++) {
                int m = rt * BM + wr * 64 + mi * 16 + quad * 4 + r;
                if (m < cnt) {
                    size_t rowbase = (size_t)(off + m) * F;
#pragma unroll
                    for (int ni = 0; ni < 4; ni++) {
                        float v = acc[mi][ni][r];
                        float u = 0.7978845608028654f * (v + 0.044715f * v * v * v);
                        float g = v / (1.f + __expf(-2.f * u));   // v * sigmoid(2u)
                        int fcol = nt * BN + wc * 64 + ni * 16 + l16;
                        hbuf[rowbase + fcol] = f2bf(g);
                    }
                }
            }
        }
    }
}

// ---------- fc2: out[tok[slot]] += gw[slot] * (h[slot] @ w2[e]) ----------
__global__ __launch_bounds__(256, 2) void fc2_kernel(const u16* __restrict__ hbuf,  // TK x F
                                                     const u16* __restrict__ w2t,   // E x H x F
                                                     const int* __restrict__ tokbuf,
                                                     const float* __restrict__ gwbuf,
                                                     const int* __restrict__ counts,
                                                     const int* __restrict__ offsets,
                                                     float* __restrict__ out) {     // T x H
    __shared__ __align__(16) u16 As[3 * BUFSZ];
    __shared__ __align__(16) u16 Bs[3 * BUFSZ];

    const int e = blockIdx.z;
    const int cnt = counts[e];
    const int off = offsets[e];
    // XCD-chunked swizzle: grid (8,16); 128 blocks/expert, 16/XCD.
    const int fhw = blockIdx.x + 8 * blockIdx.y;
    const int f   = (fhw & 7) * 16 + (fhw >> 3);
    const int nt  = f & 7;               // H/BN tile
    const int by  = f >> 3;              // M-tile start (0..15)

    const int tid = threadIdx.x;
    const int lane = tid & 63;
    const int wave = tid >> 6;
    const int wr = wave >> 1, wc = wave & 1;
    const int quad = lane >> 4, l16 = lane & 15;
    const int r0 = tid >> 2;
    const int kc = tid & 3;

    const int NS = F / BK;                 // 128 K-steps

    for (int rt = by; rt * BM < cnt; rt += 16) {
        int m0 = rt * BM + r0, m1 = m0 + 64;
        int s0 = off + (m0 < cnt ? m0 : cnt - 1);
        int s1 = off + (m1 < cnt ? m1 : cnt - 1);
        const u16* a0 = hbuf + (size_t)s0 * F + kc * 8;
        const u16* a1 = hbuf + (size_t)s1 * F + kc * 8;
        const u16* b0 = w2t + ((size_t)e * H + nt * BN + r0) * F + kc * 8;
        const u16* b1 = b0 + (size_t)64 * F;

        f32x4 acc[4][4];
#pragma unroll
        for (int i = 0; i < 4; i++)
#pragma unroll
            for (int j = 0; j < 4; j++) acc[i][j] = (f32x4)0.f;

        __builtin_amdgcn_s_barrier();
        CFENCE;
        STAGE(0, 0);
        STAGE(1, BK);

        int cur = 0;
        for (int i = 0; i < NS; ++i) {
            __builtin_amdgcn_s_barrier();
            CFENCE;
            if (i < NS - 2) {
                int s2 = (cur == 0) ? 2 : cur - 1;   // (cur+2)%3
                STAGE(s2, (i + 2) * BK);
                asm volatile("s_waitcnt vmcnt(8)" ::: "memory");
            } else if (i == NS - 2) {
                asm volatile("s_waitcnt vmcnt(4)" ::: "memory");
            } else {
                asm volatile("s_waitcnt vmcnt(0)" ::: "memory");
            }
            __builtin_amdgcn_s_barrier();
            CFENCE;

            const u16* Ab = As + cur * BUFSZ;
            const u16* Bb = Bs + cur * BUFSZ;
            bf16x8 af[4], bfv[4];
#pragma unroll
            for (int mi = 0; mi < 4; mi++)
                af[mi] = *(const bf16x8*)&Ab[(wr * 64 + mi * 16 + l16) * BK + quad * 8];
#pragma unroll
            for (int ni = 0; ni < 4; ni++)
                bfv[ni] = *(const bf16x8*)&Bb[(wc * 64 + ni * 16 + l16) * BK + quad * 8];
#pragma unroll
            for (int mi = 0; mi < 4; mi++)
#pragma unroll
                for (int ni = 0; ni < 4; ni++)
                    acc[mi][ni] = __builtin_amdgcn_mfma_f32_16x16x32_bf16(
                        af[mi], bfv[ni], acc[mi][ni], 0, 0, 0);

            cur = (cur == 2) ? 0 : cur + 1;
        }

#pragma unroll
        for (int mi = 0; mi < 4; mi++) {
#pragma unroll
            for (int r = 0; r < 4; r++) {
                int m = rt * BM + wr * 64 + mi * 16 + quad * 4 + r;
                if (m < cnt) {
                    int t = tokbuf[off + m];
                    float g = gwbuf[off + m];
                    size_t obase = (size_t)t * H;
#pragma unroll
                    for (int ni = 0; ni < 4; ni++) {
                        int col = nt * BN + wc * 64 + ni * 16 + l16;
                        atomicAdd(&out[obase + col], g * acc[mi][ni][r]);
                    }
                }
            }
        }
    }
}

// ---------- launch ----------
extern "C" void kernel_launch(void* const* d_in, const int* in_sizes, int n_in,
                              void* d_out, int out_size, void* d_ws, size_t ws_size,
                              hipStream_t stream) {
    const float* x    = (const float*)d_in[0];   // S,B,H fp32
    const float* gate = (const float*)d_in[1];   // T,K
    const int*   ce   = (const int*)d_in[2];     // T,K
    const float* w1   = (const float*)d_in[3];   // E,H,F
    const float* w2   = (const float*)d_in[4];   // E,F,H
    float* out = (float*)d_out;
    char* ws = (char*)d_ws;

    // workspace layout
    int*   counts  = (int*)(ws + 0);                 // 8
    int*   fill    = (int*)(ws + 32);                // 8
    int*   offsets = (int*)(ws + 64);                // 8
    int*   tokbuf  = (int*)(ws + 256);               // TK
    float* gwbuf   = (float*)(ws + 256 + TK * 4);    // TK
    size_t o = 256 + (size_t)TK * 8;
    u16* xb  = (u16*)(ws + o);  o += (size_t)T * H * 2;       // 16.8 MB
    u16* w1t = (u16*)(ws + o);  o += (size_t)E * F * H * 2;   // 67 MB  (E,F,H)
    u16* w2t = (u16*)(ws + o);  o += (size_t)E * H * F * 2;   // 67 MB  (E,H,F)
    u16* hbuf = (u16*)(ws + o);                                // TK x F bf16, 134 MB

    hipMemsetAsync(ws, 0, 256, stream);                        // counts + fill
    hipMemsetAsync(d_out, 0, (size_t)T * H * sizeof(float), stream);

    count_kernel<<<TK / 256, 256, 0, stream>>>(ce, counts);
    scan_kernel<<<1, 64, 0, stream>>>(counts, offsets);
    fill_kernel<<<TK / 256, 256, 0, stream>>>(ce, gate, offsets, fill, tokbuf, gwbuf);

    cvt_bf16<<<(T * H) / (256 * 4), 256, 0, stream>>>(x, xb, T * H);
    transpose_cvt<<<dim3(F / 64, H / 64, E), 256, 0, stream>>>(w1, w1t, H, F);  // (H,F)->(F,H)
    transpose_cvt<<<dim3(H / 64, F / 64, E), 256, 0, stream>>>(w2, w2t, F, H);  // (F,H)->(H,F)

    fc1_kernel<<<dim3(F / BN, 16, E), 256, 0, stream>>>(xb, w1t, tokbuf, counts, offsets, hbuf);
    fc2_kernel<<<dim3(H / BN, 16, E), 256, 0, stream>>>(hbuf, w2t, tokbuf, gwbuf, counts, offsets, out);
}

// Round 3
// 976.821 us; speedup vs baseline: 1.0810x; 1.0738x over previous
//
#include <hip/hip_runtime.h>
#include <stdint.h>

#define T 8192
#define H 1024
#define F 4096
#define E 8
#define K_TOP 2
#define TK (T * K_TOP)

#define BM 128
#define BN 128
#define BK 32

typedef unsigned short u16;
typedef __bf16 bf16x8 __attribute__((ext_vector_type(8)));
typedef float f32x4 __attribute__((ext_vector_type(4)));

// ---------- helpers ----------
__device__ __forceinline__ u16 f2bf(float f) {
    union { float f; uint32_t u; } v; v.f = f;
    uint32_t r = v.u + 0x7FFFu + ((v.u >> 16) & 1u);   // RNE
    return (u16)(r >> 16);
}

__device__ __forceinline__ void async_cp16(const u16* g, u16* l) {
    __builtin_amdgcn_global_load_lds(
        (const __attribute__((address_space(1))) void*)g,
        (__attribute__((address_space(3))) void*)l, 16, 0, 0);
}

// ---------- routing ----------
__global__ __launch_bounds__(256) void count_kernel(const int* __restrict__ ce,
                                                    int* __restrict__ counts) {
    int p = blockIdx.x * 256 + threadIdx.x;
    if (p < TK) atomicAdd(&counts[ce[p]], 1);
}

__global__ void scan_kernel(const int* __restrict__ counts, int* __restrict__ offsets) {
    if (threadIdx.x == 0) {
        int s = 0;
        for (int e = 0; e < E; e++) { offsets[e] = s; s += counts[e]; }
    }
}

__global__ __launch_bounds__(256) void fill_kernel(const int* __restrict__ ce,
                                                   const float* __restrict__ gate,
                                                   const int* __restrict__ offsets,
                                                   int* __restrict__ fill,
                                                   int* __restrict__ tokbuf,
                                                   float* __restrict__ gwbuf) {
    int p = blockIdx.x * 256 + threadIdx.x;
    if (p < TK) {
        int e = ce[p];
        int pos = offsets[e] + atomicAdd(&fill[e], 1);
        tokbuf[pos] = p >> 1;          // t = p / K_TOP (K_TOP==2)
        gwbuf[pos] = gate[p];
    }
}

// ---------- fp32 -> bf16 convert (x) ----------
__global__ __launch_bounds__(256) void cvt_bf16(const float* __restrict__ in,
                                                u16* __restrict__ out, int n) {
    int i = (blockIdx.x * 256 + threadIdx.x) * 4;
    if (i < n) {
        float4 v = *(const float4*)(in + i);
        ushort4 o;
        o.x = f2bf(v.x); o.y = f2bf(v.y); o.z = f2bf(v.z); o.w = f2bf(v.w);
        *(ushort4*)(out + i) = o;
    }
}

// ---------- fp32 (R x C) -> bf16 transposed (C x R), per expert (blockIdx.z) ----------
// Vectorized: float4 global loads, ushort4 global stores; [64][66] pad -> <=2-way.
__global__ __launch_bounds__(256) void transpose_cvt(const float* __restrict__ in,
                                                     u16* __restrict__ out,
                                                     int R, int C) {
    __shared__ u16 tile[64][66];
    int e = blockIdx.z;
    const float* src = in + (size_t)e * R * C;
    u16* dst = out + (size_t)e * R * C;
    int c0 = blockIdx.x * 64, r0 = blockIdx.y * 64;
    int q = threadIdx.x & 15;      // 4-elem chunk index
    int s = threadIdx.x >> 4;      // 0..15
#pragma unroll
    for (int p = 0; p < 4; p++) {
        int row = s + p * 16;
        float4 v = *(const float4*)(src + (size_t)(r0 + row) * C + c0 + q * 4);
        tile[row][q * 4 + 0] = f2bf(v.x);
        tile[row][q * 4 + 1] = f2bf(v.y);
        tile[row][q * 4 + 2] = f2bf(v.z);
        tile[row][q * 4 + 3] = f2bf(v.w);
    }
    __syncthreads();
#pragma unroll
    for (int p = 0; p < 4; p++) {
        int c = s + p * 16;        // orig col = output row
        ushort4 o;
        o.x = tile[q * 4 + 0][c];
        o.y = tile[q * 4 + 1][c];
        o.z = tile[q * 4 + 2][c];
        o.w = tile[q * 4 + 3][c];
        *(ushort4*)(dst + (size_t)(c0 + c) * R + r0 + q * 4) = o;
    }
}

// ---------- fc1: h[slot] = gelu(x[tok[slot]] @ w1[e])  (bf16 out) ----------
// Round-0 structure (single 16KB LDS buffer, 2 syncthreads/K-step) +
// XCD-chunked block swizzle ONLY: XCD c owns rt-band {2c,2c+1} x all nt,
// so its 2 A-panels (512KB) stay L2-resident and are reused by 32 blocks.
__global__ __launch_bounds__(256, 2) void fc1_kernel(const u16* __restrict__ xb,   // T x H
                                                     const u16* __restrict__ w1t,  // E x F x H
                                                     const int* __restrict__ tokbuf,
                                                     const int* __restrict__ counts,
                                                     const int* __restrict__ offsets,
                                                     u16* __restrict__ hbuf) {     // TK x F
    __shared__ __align__(16) u16 As[BM * BK];
    __shared__ __align__(16) u16 Bs[BN * BK];

    const int e = blockIdx.z;
    const int cnt = counts[e];
    const int off = offsets[e];
    // swizzle: XCD = linear_id & 7 = blockIdx.x & 7 (gridDim.x = 32)
    const int fhw = blockIdx.x + 32 * blockIdx.y;        // [0,512)
    const int f   = (fhw & 7) * 64 + (fhw >> 3);         // bijective
    const int nt  = f & 31;              // F/BN tile
    const int by  = f >> 5;              // M-tile start (0..15)

    const int tid = threadIdx.x;
    const int lane = tid & 63;
    const int wave = tid >> 6;
    const int wr = wave >> 1, wc = wave & 1;
    const int quad = lane >> 4, l16 = lane & 15;
    const int r0 = tid >> 2;               // staging row (0..63)
    const int kc = tid & 3;                // 16B chunk within 64B row

    for (int rt = by; rt * BM < cnt; rt += 16) {
        int m0 = rt * BM + r0, m1 = m0 + 64;
        int t0 = tokbuf[off + (m0 < cnt ? m0 : cnt - 1)];
        int t1 = tokbuf[off + (m1 < cnt ? m1 : cnt - 1)];
        const u16* a0 = xb + (size_t)t0 * H + kc * 8;
        const u16* a1 = xb + (size_t)t1 * H + kc * 8;
        const u16* b0 = w1t + ((size_t)e * F + nt * BN + r0) * H + kc * 8;
        const u16* b1 = b0 + (size_t)64 * H;

        f32x4 acc[4][4];
#pragma unroll
        for (int i = 0; i < 4; i++)
#pragma unroll
            for (int j = 0; j < 4; j++) acc[i][j] = (f32x4)0.f;

        for (int k0 = 0; k0 < H; k0 += BK) {
            __syncthreads();
            async_cp16(a0 + k0, &As[tid * 8]);
            async_cp16(a1 + k0, &As[(tid + 256) * 8]);
            async_cp16(b0 + k0, &Bs[tid * 8]);
            async_cp16(b1 + k0, &Bs[(tid + 256) * 8]);
            __syncthreads();

            bf16x8 af[4], bfv[4];
#pragma unroll
            for (int mi = 0; mi < 4; mi++)
                af[mi] = *(const bf16x8*)&As[(wr * 64 + mi * 16 + l16) * BK + quad * 8];
#pragma unroll
            for (int ni = 0; ni < 4; ni++)
                bfv[ni] = *(const bf16x8*)&Bs[(wc * 64 + ni * 16 + l16) * BK + quad * 8];
#pragma unroll
            for (int mi = 0; mi < 4; mi++)
#pragma unroll
                for (int ni = 0; ni < 4; ni++)
                    acc[mi][ni] = __builtin_amdgcn_mfma_f32_16x16x32_bf16(
                        af[mi], bfv[ni], acc[mi][ni], 0, 0, 0);
        }

        // epilogue: gelu(tanh approx) -> bf16 h
#pragma unroll
        for (int mi = 0; mi < 4; mi++) {
#pragma unroll
            for (int r = 0; r < 4; r++) {
                int m = rt * BM + wr * 64 + mi * 16 + quad * 4 + r;
                if (m < cnt) {
                    size_t rowbase = (size_t)(off + m) * F;
#pragma unroll
                    for (int ni = 0; ni < 4; ni++) {
                        float v = acc[mi][ni][r];
                        float u = 0.7978845608028654f * (v + 0.044715f * v * v * v);
                        float g = v / (1.f + __expf(-2.f * u));   // v * sigmoid(2u)
                        int fcol = nt * BN + wc * 64 + ni * 16 + l16;
                        hbuf[rowbase + fcol] = f2bf(g);
                    }
                }
            }
        }
    }
}

// ---------- fc2: out[tok[slot]] += gw[slot] * (h[slot] @ w2[e]) ----------
__global__ __launch_bounds__(256, 2) void fc2_kernel(const u16* __restrict__ hbuf,  // TK x F
                                                     const u16* __restrict__ w2t,   // E x H x F
                                                     const int* __restrict__ tokbuf,
                                                     const float* __restrict__ gwbuf,
                                                     const int* __restrict__ counts,
                                                     const int* __restrict__ offsets,
                                                     float* __restrict__ out) {     // T x H
    __shared__ __align__(16) u16 As[BM * BK];
    __shared__ __align__(16) u16 Bs[BN * BK];

    const int e = blockIdx.z;
    const int cnt = counts[e];
    const int off = offsets[e];
    // swizzle: XCD = blockIdx.x & 7 (gridDim.x = 8); XCD c -> rt-band {2c,2c+1}
    const int fhw = blockIdx.x + 8 * blockIdx.y;         // [0,128)
    const int f   = (fhw & 7) * 16 + (fhw >> 3);         // bijective
    const int nt  = f & 7;               // H/BN tile
    const int by  = f >> 3;              // M-tile start (0..15)

    const int tid = threadIdx.x;
    const int lane = tid & 63;
    const int wave = tid >> 6;
    const int wr = wave >> 1, wc = wave & 1;
    const int quad = lane >> 4, l16 = lane & 15;
    const int r0 = tid >> 2;
    const int kc = tid & 3;

    for (int rt = by; rt * BM < cnt; rt += 16) {
        int m0 = rt * BM + r0, m1 = m0 + 64;
        int s0 = off + (m0 < cnt ? m0 : cnt - 1);
        int s1 = off + (m1 < cnt ? m1 : cnt - 1);
        const u16* a0 = hbuf + (size_t)s0 * F + kc * 8;
        const u16* a1 = hbuf + (size_t)s1 * F + kc * 8;
        const u16* b0 = w2t + ((size_t)e * H + nt * BN + r0) * F + kc * 8;
        const u16* b1 = b0 + (size_t)64 * F;

        f32x4 acc[4][4];
#pragma unroll
        for (int i = 0; i < 4; i++)
#pragma unroll
            for (int j = 0; j < 4; j++) acc[i][j] = (f32x4)0.f;

        for (int k0 = 0; k0 < F; k0 += BK) {
            __syncthreads();
            async_cp16(a0 + k0, &As[tid * 8]);
            async_cp16(a1 + k0, &As[(tid + 256) * 8]);
            async_cp16(b0 + k0, &Bs[tid * 8]);
            async_cp16(b1 + k0, &Bs[(tid + 256) * 8]);
            __syncthreads();

            bf16x8 af[4], bfv[4];
#pragma unroll
            for (int mi = 0; mi < 4; mi++)
                af[mi] = *(const bf16x8*)&As[(wr * 64 + mi * 16 + l16) * BK + quad * 8];
#pragma unroll
            for (int ni = 0; ni < 4; ni++)
                bfv[ni] = *(const bf16x8*)&Bs[(wc * 64 + ni * 16 + l16) * BK + quad * 8];
#pragma unroll
            for (int mi = 0; mi < 4; mi++)
#pragma unroll
                for (int ni = 0; ni < 4; ni++)
                    acc[mi][ni] = __builtin_amdgcn_mfma_f32_16x16x32_bf16(
                        af[mi], bfv[ni], acc[mi][ni], 0, 0, 0);
        }

#pragma unroll
        for (int mi = 0; mi < 4; mi++) {
#pragma unroll
            for (int r = 0; r < 4; r++) {
                int m = rt * BM + wr * 64 + mi * 16 + quad * 4 + r;
                if (m < cnt) {
                    int t = tokbuf[off + m];
                    float g = gwbuf[off + m];
                    size_t obase = (size_t)t * H;
#pragma unroll
                    for (int ni = 0; ni < 4; ni++) {
                        int col = nt * BN + wc * 64 + ni * 16 + l16;
                        atomicAdd(&out[obase + col], g * acc[mi][ni][r]);
                    }
                }
            }
        }
    }
}

// ---------- launch ----------
extern "C" void kernel_launch(void* const* d_in, const int* in_sizes, int n_in,
                              void* d_out, int out_size, void* d_ws, size_t ws_size,
                              hipStream_t stream) {
    const float* x    = (const float*)d_in[0];   // S,B,H fp32
    const float* gate = (const float*)d_in[1];   // T,K
    const int*   ce   = (const int*)d_in[2];     // T,K
    const float* w1   = (const float*)d_in[3];   // E,H,F
    const float* w2   = (const float*)d_in[4];   // E,F,H
    float* out = (float*)d_out;
    char* ws = (char*)d_ws;

    // workspace layout
    int*   counts  = (int*)(ws + 0);                 // 8
    int*   fill    = (int*)(ws + 32);                // 8
    int*   offsets = (int*)(ws + 64);                // 8
    int*   tokbuf  = (int*)(ws + 256);               // TK
    float* gwbuf   = (float*)(ws + 256 + TK * 4);    // TK
    size_t o = 256 + (size_t)TK * 8;
    u16* xb  = (u16*)(ws + o);  o += (size_t)T * H * 2;       // 16.8 MB
    u16* w1t = (u16*)(ws + o);  o += (size_t)E * F * H * 2;   // 67 MB  (E,F,H)
    u16* w2t = (u16*)(ws + o);  o += (size_t)E * H * F * 2;   // 67 MB  (E,H,F)
    u16* hbuf = (u16*)(ws + o);                                // TK x F bf16, 134 MB

    hipMemsetAsync(ws, 0, 256, stream);                        // counts + fill
    hipMemsetAsync(d_out, 0, (size_t)T * H * sizeof(float), stream);

    count_kernel<<<TK / 256, 256, 0, stream>>>(ce, counts);
    scan_kernel<<<1, 64, 0, stream>>>(counts, offsets);
    fill_kernel<<<TK / 256, 256, 0, stream>>>(ce, gate, offsets, fill, tokbuf, gwbuf);

    cvt_bf16<<<(T * H) / (256 * 4), 256, 0, stream>>>(x, xb, T * H);
    transpose_cvt<<<dim3(F / 64, H / 64, E), 256, 0, stream>>>(w1, w1t, H, F);  // (H,F)->(F,H)
    transpose_cvt<<<dim3(H / 64, F / 64, E), 256, 0, stream>>>(w2, w2t, F, H);  // (F,H)->(H,F)

    fc1_kernel<<<dim3(F / BN, 16, E), 256, 0, stream>>>(xb, w1t, tokbuf, counts, offsets, hbuf);
    fc2_kernel<<<dim3(H / BN, 16, E), 256, 0, stream>>>(hbuf, w2t, tokbuf, gwbuf, counts, offsets, out);
}

// Round 4
// 947.465 us; speedup vs baseline: 1.1145x; 1.0310x over previous
//
#include <hip/hip_runtime.h>
#include <stdint.h>

#define T 8192
#define H 1024
#define F 4096
#define E 8
#define K_TOP 2
#define TK (T * K_TOP)

#define BM 128
#define BN 128
#define BK 64                       // doubled: halves vmcnt-drain events
#define TILEU (BM * BK)             // u16 elems per LDS operand tile (16 KB)

typedef unsigned short u16;
typedef __bf16 bf16x8 __attribute__((ext_vector_type(8)));
typedef float f32x4 __attribute__((ext_vector_type(4)));

// ---------- helpers ----------
__device__ __forceinline__ u16 f2bf(float f) {
    union { float f; uint32_t u; } v; v.f = f;
    uint32_t r = v.u + 0x7FFFu + ((v.u >> 16) & 1u);   // RNE
    return (u16)(r >> 16);
}

__device__ __forceinline__ void async_cp16(const u16* g, u16* l) {
    __builtin_amdgcn_global_load_lds(
        (const __attribute__((address_space(1))) void*)g,
        (__attribute__((address_space(3))) void*)l, 16, 0, 0);
}

// ---------- routing ----------
__global__ __launch_bounds__(256) void count_kernel(const int* __restrict__ ce,
                                                    int* __restrict__ counts) {
    int p = blockIdx.x * 256 + threadIdx.x;
    if (p < TK) atomicAdd(&counts[ce[p]], 1);
}

__global__ void scan_kernel(const int* __restrict__ counts, int* __restrict__ offsets) {
    if (threadIdx.x == 0) {
        int s = 0;
        for (int e = 0; e < E; e++) { offsets[e] = s; s += counts[e]; }
    }
}

__global__ __launch_bounds__(256) void fill_kernel(const int* __restrict__ ce,
                                                   const float* __restrict__ gate,
                                                   const int* __restrict__ offsets,
                                                   int* __restrict__ fill,
                                                   int* __restrict__ tokbuf,
                                                   float* __restrict__ gwbuf) {
    int p = blockIdx.x * 256 + threadIdx.x;
    if (p < TK) {
        int e = ce[p];
        int pos = offsets[e] + atomicAdd(&fill[e], 1);
        tokbuf[pos] = p >> 1;          // t = p / K_TOP (K_TOP==2)
        gwbuf[pos] = gate[p];
    }
}

// ---------- fp32 -> bf16 convert (x) ----------
__global__ __launch_bounds__(256) void cvt_bf16(const float* __restrict__ in,
                                                u16* __restrict__ out, int n) {
    int i = (blockIdx.x * 256 + threadIdx.x) * 4;
    if (i < n) {
        float4 v = *(const float4*)(in + i);
        ushort4 o;
        o.x = f2bf(v.x); o.y = f2bf(v.y); o.z = f2bf(v.z); o.w = f2bf(v.w);
        *(ushort4*)(out + i) = o;
    }
}

// ---------- fp32 (R x C) -> bf16 transposed (C x R), per expert (blockIdx.z) ----------
__global__ __launch_bounds__(256) void transpose_cvt(const float* __restrict__ in,
                                                     u16* __restrict__ out,
                                                     int R, int C) {
    __shared__ u16 tile[64][66];
    int e = blockIdx.z;
    const float* src = in + (size_t)e * R * C;
    u16* dst = out + (size_t)e * R * C;
    int c0 = blockIdx.x * 64, r0 = blockIdx.y * 64;
    int q = threadIdx.x & 15;      // 4-elem chunk index
    int s = threadIdx.x >> 4;      // 0..15
#pragma unroll
    for (int p = 0; p < 4; p++) {
        int row = s + p * 16;
        float4 v = *(const float4*)(src + (size_t)(r0 + row) * C + c0 + q * 4);
        tile[row][q * 4 + 0] = f2bf(v.x);
        tile[row][q * 4 + 1] = f2bf(v.y);
        tile[row][q * 4 + 2] = f2bf(v.z);
        tile[row][q * 4 + 3] = f2bf(v.w);
    }
    __syncthreads();
#pragma unroll
    for (int p = 0; p < 4; p++) {
        int c = s + p * 16;        // orig col = output row
        ushort4 o;
        o.x = tile[q * 4 + 0][c];
        o.y = tile[q * 4 + 1][c];
        o.z = tile[q * 4 + 2][c];
        o.w = tile[q * 4 + 3][c];
        *(ushort4*)(dst + (size_t)(c0 + c) * R + r0 + q * 4) = o;
    }
}

// ---------- fc1: h[slot] = gelu(x[tok[slot]] @ w1[e])  (bf16 out) ----------
// BK=64 single-buffer, 2 barriers / K-step (half as many steps as BK=32).
// LDS layout: [row][64] u16, row stride 128B.  Writes stay LINEAR for
// global_load_lds (dest == tid*16B per quarter); bank conflicts on the
// fragment reads are killed by pre-swizzling the global SOURCE 16B-chunk
// (kc ^= row&7) and XOR-ing the ds_read chunk the same way (rule #21).
__global__ __launch_bounds__(256, 2) void fc1_kernel(const u16* __restrict__ xb,   // T x H
                                                     const u16* __restrict__ w1t,  // E x F x H
                                                     const int* __restrict__ tokbuf,
                                                     const int* __restrict__ counts,
                                                     const int* __restrict__ offsets,
                                                     u16* __restrict__ hbuf) {     // TK x F
    __shared__ __align__(16) u16 As[TILEU];
    __shared__ __align__(16) u16 Bs[TILEU];

    const int e = blockIdx.z;
    const int cnt = counts[e];
    const int off = offsets[e];
    // XCD-chunked swizzle (kept: verified -42% fetch)
    const int fhw = blockIdx.x + 32 * blockIdx.y;        // [0,512)
    const int f   = (fhw & 7) * 64 + (fhw >> 3);         // bijective
    const int nt  = f & 31;              // F/BN tile
    const int by  = f >> 5;              // M-tile start (0..15)

    const int tid = threadIdx.x;
    const int lane = tid & 63;
    const int wave = tid >> 6;
    const int wr = wave >> 1, wc = wave & 1;
    const int quad = lane >> 4, l16 = lane & 15;
    const int sw = l16 & 7;                // read-side swizzle key
    const int rbase = tid >> 3;            // staging row base (0..31)
    const int kcs = ((tid & 7) ^ (rbase & 7)) * 8;   // pre-swizzled 16B chunk (u16)

    for (int rt = by; rt * BM < cnt; rt += 16) {
        const u16* ap[4];
        const u16* bp[4];
#pragma unroll
        for (int i = 0; i < 4; i++) {
            int m = rt * BM + rbase + 32 * i;
            int t = tokbuf[off + (m < cnt ? m : cnt - 1)];
            ap[i] = xb + (size_t)t * H + kcs;
            bp[i] = w1t + ((size_t)e * F + nt * BN + rbase + 32 * i) * H + kcs;
        }

        f32x4 acc[4][4];
#pragma unroll
        for (int i = 0; i < 4; i++)
#pragma unroll
            for (int j = 0; j < 4; j++) acc[i][j] = (f32x4)0.f;

        for (int k0 = 0; k0 < H; k0 += BK) {
            __syncthreads();
#pragma unroll
            for (int i = 0; i < 4; i++) {
                async_cp16(ap[i] + k0, &As[tid * 8 + i * 2048]);
                async_cp16(bp[i] + k0, &Bs[tid * 8 + i * 2048]);
            }
            __syncthreads();

#pragma unroll
            for (int ks = 0; ks < 2; ks++) {
                bf16x8 af[4], bfv[4];
#pragma unroll
                for (int mi = 0; mi < 4; mi++)
                    af[mi] = *(const bf16x8*)&As[(wr * 64 + mi * 16 + l16) * BK
                                                 + (((ks * 4 + quad) ^ sw) * 8)];
#pragma unroll
                for (int ni = 0; ni < 4; ni++)
                    bfv[ni] = *(const bf16x8*)&Bs[(wc * 64 + ni * 16 + l16) * BK
                                                  + (((ks * 4 + quad) ^ sw) * 8)];
#pragma unroll
                for (int mi = 0; mi < 4; mi++)
#pragma unroll
                    for (int ni = 0; ni < 4; ni++)
                        acc[mi][ni] = __builtin_amdgcn_mfma_f32_16x16x32_bf16(
                            af[mi], bfv[ni], acc[mi][ni], 0, 0, 0);
            }
        }

        // epilogue: gelu(tanh approx) -> bf16 h
#pragma unroll
        for (int mi = 0; mi < 4; mi++) {
#pragma unroll
            for (int r = 0; r < 4; r++) {
                int m = rt * BM + wr * 64 + mi * 16 + quad * 4 + r;
                if (m < cnt) {
                    size_t rowbase = (size_t)(off + m) * F;
#pragma unroll
                    for (int ni = 0; ni < 4; ni++) {
                        float v = acc[mi][ni][r];
                        float u = 0.7978845608028654f * (v + 0.044715f * v * v * v);
                        float g = v / (1.f + __expf(-2.f * u));   // v * sigmoid(2u)
                        int fcol = nt * BN + wc * 64 + ni * 16 + l16;
                        hbuf[rowbase + fcol] = f2bf(g);
                    }
                }
            }
        }
    }
}

// ---------- fc2: out[tok[slot]] += gw[slot] * (h[slot] @ w2[e]) ----------
__global__ __launch_bounds__(256, 2) void fc2_kernel(const u16* __restrict__ hbuf,  // TK x F
                                                     const u16* __restrict__ w2t,   // E x H x F
                                                     const int* __restrict__ tokbuf,
                                                     const float* __restrict__ gwbuf,
                                                     const int* __restrict__ counts,
                                                     const int* __restrict__ offsets,
                                                     float* __restrict__ out) {     // T x H
    __shared__ __align__(16) u16 As[TILEU];
    __shared__ __align__(16) u16 Bs[TILEU];

    const int e = blockIdx.z;
    const int cnt = counts[e];
    const int off = offsets[e];
    const int fhw = blockIdx.x + 8 * blockIdx.y;         // [0,128)
    const int f   = (fhw & 7) * 16 + (fhw >> 3);         // bijective
    const int nt  = f & 7;               // H/BN tile
    const int by  = f >> 3;              // M-tile start (0..15)

    const int tid = threadIdx.x;
    const int lane = tid & 63;
    const int wave = tid >> 6;
    const int wr = wave >> 1, wc = wave & 1;
    const int quad = lane >> 4, l16 = lane & 15;
    const int sw = l16 & 7;
    const int rbase = tid >> 3;
    const int kcs = ((tid & 7) ^ (rbase & 7)) * 8;

    for (int rt = by; rt * BM < cnt; rt += 16) {
        const u16* ap[4];
        const u16* bp[4];
#pragma unroll
        for (int i = 0; i < 4; i++) {
            int m = rt * BM + rbase + 32 * i;
            int s = off + (m < cnt ? m : cnt - 1);
            ap[i] = hbuf + (size_t)s * F + kcs;
            bp[i] = w2t + ((size_t)e * H + nt * BN + rbase + 32 * i) * F + kcs;
        }

        f32x4 acc[4][4];
#pragma unroll
        for (int i = 0; i < 4; i++)
#pragma unroll
            for (int j = 0; j < 4; j++) acc[i][j] = (f32x4)0.f;

        for (int k0 = 0; k0 < F; k0 += BK) {
            __syncthreads();
#pragma unroll
            for (int i = 0; i < 4; i++) {
                async_cp16(ap[i] + k0, &As[tid * 8 + i * 2048]);
                async_cp16(bp[i] + k0, &Bs[tid * 8 + i * 2048]);
            }
            __syncthreads();

#pragma unroll
            for (int ks = 0; ks < 2; ks++) {
                bf16x8 af[4], bfv[4];
#pragma unroll
                for (int mi = 0; mi < 4; mi++)
                    af[mi] = *(const bf16x8*)&As[(wr * 64 + mi * 16 + l16) * BK
                                                 + (((ks * 4 + quad) ^ sw) * 8)];
#pragma unroll
                for (int ni = 0; ni < 4; ni++)
                    bfv[ni] = *(const bf16x8*)&Bs[(wc * 64 + ni * 16 + l16) * BK
                                                  + (((ks * 4 + quad) ^ sw) * 8)];
#pragma unroll
                for (int mi = 0; mi < 4; mi++)
#pragma unroll
                    for (int ni = 0; ni < 4; ni++)
                        acc[mi][ni] = __builtin_amdgcn_mfma_f32_16x16x32_bf16(
                            af[mi], bfv[ni], acc[mi][ni], 0, 0, 0);
            }
        }

#pragma unroll
        for (int mi = 0; mi < 4; mi++) {
#pragma unroll
            for (int r = 0; r < 4; r++) {
                int m = rt * BM + wr * 64 + mi * 16 + quad * 4 + r;
                if (m < cnt) {
                    int t = tokbuf[off + m];
                    float g = gwbuf[off + m];
                    size_t obase = (size_t)t * H;
#pragma unroll
                    for (int ni = 0; ni < 4; ni++) {
                        int col = nt * BN + wc * 64 + ni * 16 + l16;
                        atomicAdd(&out[obase + col], g * acc[mi][ni][r]);
                    }
                }
            }
        }
    }
}

// ---------- launch ----------
extern "C" void kernel_launch(void* const* d_in, const int* in_sizes, int n_in,
                              void* d_out, int out_size, void* d_ws, size_t ws_size,
                              hipStream_t stream) {
    const float* x    = (const float*)d_in[0];   // S,B,H fp32
    const float* gate = (const float*)d_in[1];   // T,K
    const int*   ce   = (const int*)d_in[2];     // T,K
    const float* w1   = (const float*)d_in[3];   // E,H,F
    const float* w2   = (const float*)d_in[4];   // E,F,H
    float* out = (float*)d_out;
    char* ws = (char*)d_ws;

    // workspace layout
    int*   counts  = (int*)(ws + 0);                 // 8
    int*   fill    = (int*)(ws + 32);                // 8
    int*   offsets = (int*)(ws + 64);                // 8
    int*   tokbuf  = (int*)(ws + 256);               // TK
    float* gwbuf   = (float*)(ws + 256 + TK * 4);    // TK
    size_t o = 256 + (size_t)TK * 8;
    u16* xb  = (u16*)(ws + o);  o += (size_t)T * H * 2;       // 16.8 MB
    u16* w1t = (u16*)(ws + o);  o += (size_t)E * F * H * 2;   // 67 MB  (E,F,H)
    u16* w2t = (u16*)(ws + o);  o += (size_t)E * H * F * 2;   // 67 MB  (E,H,F)
    u16* hbuf = (u16*)(ws + o);                                // TK x F bf16, 134 MB

    hipMemsetAsync(ws, 0, 256, stream);                        // counts + fill
    hipMemsetAsync(d_out, 0, (size_t)T * H * sizeof(float), stream);

    count_kernel<<<TK / 256, 256, 0, stream>>>(ce, counts);
    scan_kernel<<<1, 64, 0, stream>>>(counts, offsets);
    fill_kernel<<<TK / 256, 256, 0, stream>>>(ce, gate, offsets, fill, tokbuf, gwbuf);

    cvt_bf16<<<(T * H) / (256 * 4), 256, 0, stream>>>(x, xb, T * H);
    transpose_cvt<<<dim3(F / 64, H / 64, E), 256, 0, stream>>>(w1, w1t, H, F);  // (H,F)->(F,H)
    transpose_cvt<<<dim3(H / 64, F / 64, E), 256, 0, stream>>>(w2, w2t, F, H);  // (F,H)->(H,F)

    fc1_kernel<<<dim3(F / BN, 16, E), 256, 0, stream>>>(xb, w1t, tokbuf, counts, offsets, hbuf);
    fc2_kernel<<<dim3(H / BN, 16, E), 256, 0, stream>>>(hbuf, w2t, tokbuf, gwbuf, counts, offsets, out);
}

// Round 5
// 942.663 us; speedup vs baseline: 1.1202x; 1.0051x over previous
//
#include <hip/hip_runtime.h>
#include <stdint.h>

#define T 8192
#define H 1024
#define F 4096
#define E 8
#define K_TOP 2
#define TK (T * K_TOP)

#define BM 128
#define BN 128
#define BK 32

typedef unsigned short u16;
typedef __bf16 bf16x8 __attribute__((ext_vector_type(8)));
typedef float f32x4 __attribute__((ext_vector_type(4)));
typedef unsigned short u16x8 __attribute__((ext_vector_type(8)));

// ---------- helpers ----------
__device__ __forceinline__ u16 f2bf(float f) {
    union { float f; uint32_t u; } v; v.f = f;
    uint32_t r = v.u + 0x7FFFu + ((v.u >> 16) & 1u);   // RNE
    return (u16)(r >> 16);
}

__device__ __forceinline__ void async_cp16(const u16* g, u16* l) {
    __builtin_amdgcn_global_load_lds(
        (const __attribute__((address_space(1))) void*)g,
        (__attribute__((address_space(3))) void*)l, 16, 0, 0);
}

// ---------- routing ----------
__global__ __launch_bounds__(256) void count_kernel(const int* __restrict__ ce,
                                                    int* __restrict__ counts) {
    int p = blockIdx.x * 256 + threadIdx.x;
    if (p < TK) atomicAdd(&counts[ce[p]], 1);
}

__global__ void scan_kernel(const int* __restrict__ counts, int* __restrict__ offsets) {
    if (threadIdx.x == 0) {
        int s = 0;
        for (int e = 0; e < E; e++) { offsets[e] = s; s += counts[e]; }
    }
}

__global__ __launch_bounds__(256) void fill_kernel(const int* __restrict__ ce,
                                                   const float* __restrict__ gate,
                                                   const int* __restrict__ offsets,
                                                   int* __restrict__ fill,
                                                   int* __restrict__ tokbuf,
                                                   float* __restrict__ gwbuf) {
    int p = blockIdx.x * 256 + threadIdx.x;
    if (p < TK) {
        int e = ce[p];
        int pos = offsets[e] + atomicAdd(&fill[e], 1);
        tokbuf[pos] = p >> 1;          // t = p / K_TOP (K_TOP==2)
        gwbuf[pos] = gate[p];
    }
}

// ---------- fused preprocessing: both weight transposes + x cvt, ONE launch ----
// z in [0,8): w1 expert z, (H,F) fp32 -> (F,H) bf16
// z in [8,16): w2 expert z-8, (F,H) fp32 -> (H,F) bf16
// z == 16: cvt x -> xb (bf16), 4 grid-stride chunks
// Transpose tile 64x64: float4 loads (16B/lane), ushort8 stores (16B/lane).
__global__ __launch_bounds__(256) void prep_kernel(const float* __restrict__ x,
                                                   const float* __restrict__ w1,
                                                   const float* __restrict__ w2,
                                                   u16* __restrict__ xb,
                                                   u16* __restrict__ w1t,
                                                   u16* __restrict__ w2t) {
    const int z = blockIdx.z;
    if (z == 16) {
        // ---- cvt: 1024 blocks x 256 thr x 8 elems x 4 chunks = T*H ----
        int base = (blockIdx.y * 64 + blockIdx.x) * 256 + threadIdx.x;
#pragma unroll
        for (int p = 0; p < 4; p++) {
            int i = (base + p * 262144) * 8;
            float4 v0 = *(const float4*)(x + i);
            float4 v1 = *(const float4*)(x + i + 4);
            u16x8 o;
            o[0] = f2bf(v0.x); o[1] = f2bf(v0.y); o[2] = f2bf(v0.z); o[3] = f2bf(v0.w);
            o[4] = f2bf(v1.x); o[5] = f2bf(v1.y); o[6] = f2bf(v1.z); o[7] = f2bf(v1.w);
            *(u16x8*)(xb + i) = o;
        }
        return;
    }

    __shared__ u16 tile[64][66];
    const float* src; u16* dst; int R, C, c0, r0;
    if (z < 8) {
        src = w1 + (size_t)z * H * F;  dst = w1t + (size_t)z * H * F;
        R = H; C = F;
        c0 = blockIdx.x * 64;          // C/64 = 64 tiles
        r0 = blockIdx.y * 64;          // R/64 = 16 tiles
    } else {
        int e = z - 8;
        src = w2 + (size_t)e * F * H;  dst = w2t + (size_t)e * F * H;
        R = F; C = H;
        c0 = blockIdx.y * 64;          // C/64 = 16 tiles
        r0 = blockIdx.x * 64;          // R/64 = 64 tiles
    }

    const int q = threadIdx.x & 15;    // 16B chunk (4 fp32)
    const int s = threadIdx.x >> 4;    // 0..15
#pragma unroll
    for (int p = 0; p < 4; p++) {
        int row = s + p * 16;
        float4 v = *(const float4*)(src + (size_t)(r0 + row) * C + c0 + q * 4);
        tile[row][q * 4 + 0] = f2bf(v.x);
        tile[row][q * 4 + 1] = f2bf(v.y);
        tile[row][q * 4 + 2] = f2bf(v.z);
        tile[row][q * 4 + 3] = f2bf(v.w);
    }
    __syncthreads();
#pragma unroll
    for (int pass = 0; pass < 2; pass++) {
        int idx = threadIdx.x + pass * 256;   // [0,512)
        int c = idx >> 3;                     // out row (orig col), 0..63
        int rch = idx & 7;                    // 8-elem chunk along orig rows
        u16x8 o;
#pragma unroll
        for (int i = 0; i < 8; i++) o[i] = tile[rch * 8 + i][c];
        *(u16x8*)(dst + (size_t)(c0 + c) * R + r0 + rch * 8) = o;   // 16B store
    }
}

// ---------- fc1: h[slot] = gelu(x[tok[slot]] @ w1[e])  (bf16 out) ----------
// EXACT round-0 structure (best measured 285us-class): single 16KB LDS,
// 2 syncthreads per BK=32 K-step, no swizzle.
__global__ __launch_bounds__(256, 2) void fc1_kernel(const u16* __restrict__ xb,   // T x H
                                                     const u16* __restrict__ w1t,  // E x F x H
                                                     const int* __restrict__ tokbuf,
                                                     const int* __restrict__ counts,
                                                     const int* __restrict__ offsets,
                                                     u16* __restrict__ hbuf) {     // TK x F
    __shared__ __align__(16) u16 As[BM * BK];
    __shared__ __align__(16) u16 Bs[BN * BK];

    const int e = blockIdx.z;
    const int cnt = counts[e];
    const int off = offsets[e];
    const int nt = blockIdx.x;             // F / BN tiles
    const int tid = threadIdx.x;
    const int lane = tid & 63;
    const int wave = tid >> 6;
    const int wr = wave >> 1, wc = wave & 1;
    const int quad = lane >> 4, l16 = lane & 15;
    const int r0 = tid >> 2;               // staging row (0..63)
    const int kc = tid & 3;                // 16B chunk within 64B row

    for (int rt = blockIdx.y; rt * BM < cnt; rt += gridDim.y) {
        int m0 = rt * BM + r0, m1 = m0 + 64;
        int t0 = tokbuf[off + (m0 < cnt ? m0 : cnt - 1)];
        int t1 = tokbuf[off + (m1 < cnt ? m1 : cnt - 1)];
        const u16* a0 = xb + (size_t)t0 * H + kc * 8;
        const u16* a1 = xb + (size_t)t1 * H + kc * 8;
        const u16* b0 = w1t + ((size_t)e * F + nt * BN + r0) * H + kc * 8;
        const u16* b1 = b0 + (size_t)64 * H;

        f32x4 acc[4][4];
#pragma unroll
        for (int i = 0; i < 4; i++)
#pragma unroll
            for (int j = 0; j < 4; j++) acc[i][j] = (f32x4)0.f;

        for (int k0 = 0; k0 < H; k0 += BK) {
            __syncthreads();
            async_cp16(a0 + k0, &As[tid * 8]);
            async_cp16(a1 + k0, &As[(tid + 256) * 8]);
            async_cp16(b0 + k0, &Bs[tid * 8]);
            async_cp16(b1 + k0, &Bs[(tid + 256) * 8]);
            __syncthreads();

            bf16x8 af[4], bfv[4];
#pragma unroll
            for (int mi = 0; mi < 4; mi++)
                af[mi] = *(const bf16x8*)&As[(wr * 64 + mi * 16 + l16) * BK + quad * 8];
#pragma unroll
            for (int ni = 0; ni < 4; ni++)
                bfv[ni] = *(const bf16x8*)&Bs[(wc * 64 + ni * 16 + l16) * BK + quad * 8];
#pragma unroll
            for (int mi = 0; mi < 4; mi++)
#pragma unroll
                for (int ni = 0; ni < 4; ni++)
                    acc[mi][ni] = __builtin_amdgcn_mfma_f32_16x16x32_bf16(
                        af[mi], bfv[ni], acc[mi][ni], 0, 0, 0);
        }

        // epilogue: gelu(tanh approx) -> bf16 h
#pragma unroll
        for (int mi = 0; mi < 4; mi++) {
#pragma unroll
            for (int r = 0; r < 4; r++) {
                int m = rt * BM + wr * 64 + mi * 16 + quad * 4 + r;
                if (m < cnt) {
                    size_t rowbase = (size_t)(off + m) * F;
#pragma unroll
                    for (int ni = 0; ni < 4; ni++) {
                        float v = acc[mi][ni][r];
                        float u = 0.7978845608028654f * (v + 0.044715f * v * v * v);
                        float g = v / (1.f + __expf(-2.f * u));   // v * sigmoid(2u)
                        int fcol = nt * BN + wc * 64 + ni * 16 + l16;
                        hbuf[rowbase + fcol] = f2bf(g);
                    }
                }
            }
        }
    }
}

// ---------- fc2: out[tok[slot]] += gw[slot] * (h[slot] @ w2[e]) ----------
__global__ __launch_bounds__(256, 2) void fc2_kernel(const u16* __restrict__ hbuf,  // TK x F
                                                     const u16* __restrict__ w2t,   // E x H x F
                                                     const int* __restrict__ tokbuf,
                                                     const float* __restrict__ gwbuf,
                                                     const int* __restrict__ counts,
                                                     const int* __restrict__ offsets,
                                                     float* __restrict__ out) {     // T x H
    __shared__ __align__(16) u16 As[BM * BK];
    __shared__ __align__(16) u16 Bs[BN * BK];

    const int e = blockIdx.z;
    const int cnt = counts[e];
    const int off = offsets[e];
    const int nt = blockIdx.x;             // H / BN tiles
    const int tid = threadIdx.x;
    const int lane = tid & 63;
    const int wave = tid >> 6;
    const int wr = wave >> 1, wc = wave & 1;
    const int quad = lane >> 4, l16 = lane & 15;
    const int r0 = tid >> 2;
    const int kc = tid & 3;

    for (int rt = blockIdx.y; rt * BM < cnt; rt += gridDim.y) {
        int m0 = rt * BM + r0, m1 = m0 + 64;
        int s0 = off + (m0 < cnt ? m0 : cnt - 1);
        int s1 = off + (m1 < cnt ? m1 : cnt - 1);
        const u16* a0 = hbuf + (size_t)s0 * F + kc * 8;
        const u16* a1 = hbuf + (size_t)s1 * F + kc * 8;
        const u16* b0 = w2t + ((size_t)e * H + nt * BN + r0) * F + kc * 8;
        const u16* b1 = b0 + (size_t)64 * F;

        f32x4 acc[4][4];
#pragma unroll
        for (int i = 0; i < 4; i++)
#pragma unroll
            for (int j = 0; j < 4; j++) acc[i][j] = (f32x4)0.f;

        for (int k0 = 0; k0 < F; k0 += BK) {
            __syncthreads();
            async_cp16(a0 + k0, &As[tid * 8]);
            async_cp16(a1 + k0, &As[(tid + 256) * 8]);
            async_cp16(b0 + k0, &Bs[tid * 8]);
            async_cp16(b1 + k0, &Bs[(tid + 256) * 8]);
            __syncthreads();

            bf16x8 af[4], bfv[4];
#pragma unroll
            for (int mi = 0; mi < 4; mi++)
                af[mi] = *(const bf16x8*)&As[(wr * 64 + mi * 16 + l16) * BK + quad * 8];
#pragma unroll
            for (int ni = 0; ni < 4; ni++)
                bfv[ni] = *(const bf16x8*)&Bs[(wc * 64 + ni * 16 + l16) * BK + quad * 8];
#pragma unroll
            for (int mi = 0; mi < 4; mi++)
#pragma unroll
                for (int ni = 0; ni < 4; ni++)
                    acc[mi][ni] = __builtin_amdgcn_mfma_f32_16x16x32_bf16(
                        af[mi], bfv[ni], acc[mi][ni], 0, 0, 0);
        }

#pragma unroll
        for (int mi = 0; mi < 4; mi++) {
#pragma unroll
            for (int r = 0; r < 4; r++) {
                int m = rt * BM + wr * 64 + mi * 16 + quad * 4 + r;
                if (m < cnt) {
                    int t = tokbuf[off + m];
                    float g = gwbuf[off + m];
                    size_t obase = (size_t)t * H;
#pragma unroll
                    for (int ni = 0; ni < 4; ni++) {
                        int col = nt * BN + wc * 64 + ni * 16 + l16;
                        atomicAdd(&out[obase + col], g * acc[mi][ni][r]);
                    }
                }
            }
        }
    }
}

// ---------- launch ----------
extern "C" void kernel_launch(void* const* d_in, const int* in_sizes, int n_in,
                              void* d_out, int out_size, void* d_ws, size_t ws_size,
                              hipStream_t stream) {
    const float* x    = (const float*)d_in[0];   // S,B,H fp32
    const float* gate = (const float*)d_in[1];   // T,K
    const int*   ce   = (const int*)d_in[2];     // T,K
    const float* w1   = (const float*)d_in[3];   // E,H,F
    const float* w2   = (const float*)d_in[4];   // E,F,H
    float* out = (float*)d_out;
    char* ws = (char*)d_ws;

    // workspace layout
    int*   counts  = (int*)(ws + 0);                 // 8
    int*   fill    = (int*)(ws + 32);                // 8
    int*   offsets = (int*)(ws + 64);                // 8
    int*   tokbuf  = (int*)(ws + 256);               // TK
    float* gwbuf   = (float*)(ws + 256 + TK * 4);    // TK
    size_t o = 256 + (size_t)TK * 8;
    u16* xb  = (u16*)(ws + o);  o += (size_t)T * H * 2;       // 16.8 MB
    u16* w1t = (u16*)(ws + o);  o += (size_t)E * F * H * 2;   // 67 MB  (E,F,H)
    u16* w2t = (u16*)(ws + o);  o += (size_t)E * H * F * 2;   // 67 MB  (E,H,F)
    u16* hbuf = (u16*)(ws + o);                                // TK x F bf16, 134 MB

    hipMemsetAsync(ws, 0, 256, stream);                        // counts + fill
    hipMemsetAsync(d_out, 0, (size_t)T * H * sizeof(float), stream);

    count_kernel<<<TK / 256, 256, 0, stream>>>(ce, counts);
    scan_kernel<<<1, 64, 0, stream>>>(counts, offsets);
    fill_kernel<<<TK / 256, 256, 0, stream>>>(ce, gate, offsets, fill, tokbuf, gwbuf);

    // fused: w1 transpose (z<8), w2 transpose (z in 8..15), x cvt (z==16)
    prep_kernel<<<dim3(64, 16, 17), 256, 0, stream>>>(x, w1, w2, xb, w1t, w2t);

    fc1_kernel<<<dim3(F / BN, 32, E), 256, 0, stream>>>(xb, w1t, tokbuf, counts, offsets, hbuf);
    fc2_kernel<<<dim3(H / BN, 32, E), 256, 0, stream>>>(hbuf, w2t, tokbuf, gwbuf, counts, offsets, out);
}

// Round 6
// 826.798 us; speedup vs baseline: 1.2771x; 1.1401x over previous
//
#include <hip/hip_runtime.h>
#include <stdint.h>

#define T 8192
#define H 1024
#define F 4096
#define E 8
#define K_TOP 2
#define TK (T * K_TOP)

#define BM 128
#define BN 128
#define BK 32

typedef unsigned short u16;
typedef __bf16 bf16x8 __attribute__((ext_vector_type(8)));
typedef float f32x4 __attribute__((ext_vector_type(4)));
typedef unsigned short u16x8 __attribute__((ext_vector_type(8)));

// ---------- helpers ----------
__device__ __forceinline__ u16 f2bf(float f) {
    union { float f; uint32_t u; } v; v.f = f;
    uint32_t r = v.u + 0x7FFFu + ((v.u >> 16) & 1u);   // RNE
    return (u16)(r >> 16);
}

__device__ __forceinline__ void async_cp16(const u16* g, u16* l) {
    __builtin_amdgcn_global_load_lds(
        (const __attribute__((address_space(1))) void*)g,
        (__attribute__((address_space(3))) void*)l, 16, 0, 0);
}

// ---------- fused preprocessing (ONE launch, replaces 5 dispatches) ----------
// z in [0,8):  w1 expert z, (H,F) fp32 -> (F,H) bf16 transpose
// z in [8,16): w2 expert z-8, (F,H) fp32 -> (H,F) bf16 transpose
// z == 16:     cvt x -> xb (bf16)
// z == 17:     block 0: routing (count+scan+fill via LDS atomics, NO global
//              atomic storm); blocks 1..1023: zero d_out (replaces memset)
__global__ __launch_bounds__(256) void prep_kernel(const float* __restrict__ x,
                                                   const float* __restrict__ w1,
                                                   const float* __restrict__ w2,
                                                   const float* __restrict__ gate,
                                                   const int* __restrict__ ce,
                                                   u16* __restrict__ xb,
                                                   u16* __restrict__ w1t,
                                                   u16* __restrict__ w2t,
                                                   int* __restrict__ counts,
                                                   int* __restrict__ offsets,
                                                   int* __restrict__ tokbuf,
                                                   float* __restrict__ gwbuf,
                                                   float* __restrict__ out) {
    const int z = blockIdx.z;
    const int tid = threadIdx.x;

    if (z == 17) {
        const int lid = blockIdx.y * 64 + blockIdx.x;   // [0,1024)
        if (lid == 0) {
            // ---- routing: one block, LDS atomics only ----
            __shared__ int lcnt[E];
            __shared__ int loff[E];
            if (tid < E) lcnt[tid] = 0;
            __syncthreads();
            for (int p = tid; p < TK; p += 256)
                atomicAdd(&lcnt[ce[p]], 1);
            __syncthreads();
            if (tid == 0) {
                int s = 0;
                for (int e = 0; e < E; e++) {
                    loff[e] = s;
                    offsets[e] = s;
                    counts[e] = lcnt[e];
                    s += lcnt[e];
                }
            }
            __syncthreads();
            if (tid < E) lcnt[tid] = 0;     // reuse as fill counters
            __syncthreads();
            for (int p = tid; p < TK; p += 256) {
                int e = ce[p];
                int pos = loff[e] + atomicAdd(&lcnt[e], 1);
                tokbuf[pos] = p >> 1;       // t = p / K_TOP (K_TOP==2)
                gwbuf[pos] = gate[p];
            }
        } else {
            // ---- zero d_out: 1023 blocks, float4 grid-stride ----
            const int n4 = (T * H) / 4;
            const int stride = 1023 * 256;
            for (int i = (lid - 1) * 256 + tid; i < n4; i += stride)
                ((float4*)out)[i] = make_float4(0.f, 0.f, 0.f, 0.f);
        }
        return;
    }

    if (z == 16) {
        // ---- cvt x: 1024 blocks x 256 thr x 8 elems x 4 chunks = T*H ----
        int base = (blockIdx.y * 64 + blockIdx.x) * 256 + tid;
#pragma unroll
        for (int p = 0; p < 4; p++) {
            int i = (base + p * 262144) * 8;
            float4 v0 = *(const float4*)(x + i);
            float4 v1 = *(const float4*)(x + i + 4);
            u16x8 o;
            o[0] = f2bf(v0.x); o[1] = f2bf(v0.y); o[2] = f2bf(v0.z); o[3] = f2bf(v0.w);
            o[4] = f2bf(v1.x); o[5] = f2bf(v1.y); o[6] = f2bf(v1.z); o[7] = f2bf(v1.w);
            *(u16x8*)(xb + i) = o;
        }
        return;
    }

    // ---- weight transpose 64x64 tile ----
    __shared__ u16 tile[64][66];
    const float* src; u16* dst; int R, C, c0, r0;
    if (z < 8) {
        src = w1 + (size_t)z * H * F;  dst = w1t + (size_t)z * H * F;
        R = H; C = F;
        c0 = blockIdx.x * 64;          // C/64 = 64 tiles
        r0 = blockIdx.y * 64;          // R/64 = 16 tiles
    } else {
        int e = z - 8;
        src = w2 + (size_t)e * F * H;  dst = w2t + (size_t)e * F * H;
        R = F; C = H;
        c0 = blockIdx.y * 64;          // C/64 = 16 tiles
        r0 = blockIdx.x * 64;          // R/64 = 64 tiles
    }

    const int q = tid & 15;    // 16B chunk (4 fp32)
    const int s = tid >> 4;    // 0..15
#pragma unroll
    for (int p = 0; p < 4; p++) {
        int row = s + p * 16;
        float4 v = *(const float4*)(src + (size_t)(r0 + row) * C + c0 + q * 4);
        tile[row][q * 4 + 0] = f2bf(v.x);
        tile[row][q * 4 + 1] = f2bf(v.y);
        tile[row][q * 4 + 2] = f2bf(v.z);
        tile[row][q * 4 + 3] = f2bf(v.w);
    }
    __syncthreads();
#pragma unroll
    for (int pass = 0; pass < 2; pass++) {
        int idx = tid + pass * 256;           // [0,512)
        int c = idx >> 3;                     // out row (orig col), 0..63
        int rch = idx & 7;                    // 8-elem chunk along orig rows
        u16x8 o;
#pragma unroll
        for (int i = 0; i < 8; i++) o[i] = tile[rch * 8 + i][c];
        *(u16x8*)(dst + (size_t)(c0 + c) * R + r0 + rch * 8) = o;   // 16B store
    }
}

// ---------- fc1: h[slot] = gelu(x[tok[slot]] @ w1[e])  (bf16 out) ----------
// EXACT round-0 structure (measured best): single 16KB LDS, 2 syncthreads
// per BK=32 K-step, no swizzle. DO NOT TOUCH (rounds 1/2/4 all regressed it).
__global__ __launch_bounds__(256, 2) void fc1_kernel(const u16* __restrict__ xb,   // T x H
                                                     const u16* __restrict__ w1t,  // E x F x H
                                                     const int* __restrict__ tokbuf,
                                                     const int* __restrict__ counts,
                                                     const int* __restrict__ offsets,
                                                     u16* __restrict__ hbuf) {     // TK x F
    __shared__ __align__(16) u16 As[BM * BK];
    __shared__ __align__(16) u16 Bs[BN * BK];

    const int e = blockIdx.z;
    const int cnt = counts[e];
    const int off = offsets[e];
    const int nt = blockIdx.x;             // F / BN tiles
    const int tid = threadIdx.x;
    const int lane = tid & 63;
    const int wave = tid >> 6;
    const int wr = wave >> 1, wc = wave & 1;
    const int quad = lane >> 4, l16 = lane & 15;
    const int r0 = tid >> 2;               // staging row (0..63)
    const int kc = tid & 3;                // 16B chunk within 64B row

    for (int rt = blockIdx.y; rt * BM < cnt; rt += gridDim.y) {
        int m0 = rt * BM + r0, m1 = m0 + 64;
        int t0 = tokbuf[off + (m0 < cnt ? m0 : cnt - 1)];
        int t1 = tokbuf[off + (m1 < cnt ? m1 : cnt - 1)];
        const u16* a0 = xb + (size_t)t0 * H + kc * 8;
        const u16* a1 = xb + (size_t)t1 * H + kc * 8;
        const u16* b0 = w1t + ((size_t)e * F + nt * BN + r0) * H + kc * 8;
        const u16* b1 = b0 + (size_t)64 * H;

        f32x4 acc[4][4];
#pragma unroll
        for (int i = 0; i < 4; i++)
#pragma unroll
            for (int j = 0; j < 4; j++) acc[i][j] = (f32x4)0.f;

        for (int k0 = 0; k0 < H; k0 += BK) {
            __syncthreads();
            async_cp16(a0 + k0, &As[tid * 8]);
            async_cp16(a1 + k0, &As[(tid + 256) * 8]);
            async_cp16(b0 + k0, &Bs[tid * 8]);
            async_cp16(b1 + k0, &Bs[(tid + 256) * 8]);
            __syncthreads();

            bf16x8 af[4], bfv[4];
#pragma unroll
            for (int mi = 0; mi < 4; mi++)
                af[mi] = *(const bf16x8*)&As[(wr * 64 + mi * 16 + l16) * BK + quad * 8];
#pragma unroll
            for (int ni = 0; ni < 4; ni++)
                bfv[ni] = *(const bf16x8*)&Bs[(wc * 64 + ni * 16 + l16) * BK + quad * 8];
#pragma unroll
            for (int mi = 0; mi < 4; mi++)
#pragma unroll
                for (int ni = 0; ni < 4; ni++)
                    acc[mi][ni] = __builtin_amdgcn_mfma_f32_16x16x32_bf16(
                        af[mi], bfv[ni], acc[mi][ni], 0, 0, 0);
        }

        // epilogue: gelu(tanh approx) -> bf16 h
#pragma unroll
        for (int mi = 0; mi < 4; mi++) {
#pragma unroll
            for (int r = 0; r < 4; r++) {
                int m = rt * BM + wr * 64 + mi * 16 + quad * 4 + r;
                if (m < cnt) {
                    size_t rowbase = (size_t)(off + m) * F;
#pragma unroll
                    for (int ni = 0; ni < 4; ni++) {
                        float v = acc[mi][ni][r];
                        float u = 0.7978845608028654f * (v + 0.044715f * v * v * v);
                        float g = v / (1.f + __expf(-2.f * u));   // v * sigmoid(2u)
                        int fcol = nt * BN + wc * 64 + ni * 16 + l16;
                        hbuf[rowbase + fcol] = f2bf(g);
                    }
                }
            }
        }
    }
}

// ---------- fc2: out[tok[slot]] += gw[slot] * (h[slot] @ w2[e]) ----------
__global__ __launch_bounds__(256, 2) void fc2_kernel(const u16* __restrict__ hbuf,  // TK x F
                                                     const u16* __restrict__ w2t,   // E x H x F
                                                     const int* __restrict__ tokbuf,
                                                     const float* __restrict__ gwbuf,
                                                     const int* __restrict__ counts,
                                                     const int* __restrict__ offsets,
                                                     float* __restrict__ out) {     // T x H
    __shared__ __align__(16) u16 As[BM * BK];
    __shared__ __align__(16) u16 Bs[BN * BK];

    const int e = blockIdx.z;
    const int cnt = counts[e];
    const int off = offsets[e];
    const int nt = blockIdx.x;             // H / BN tiles
    const int tid = threadIdx.x;
    const int lane = tid & 63;
    const int wave = tid >> 6;
    const int wr = wave >> 1, wc = wave & 1;
    const int quad = lane >> 4, l16 = lane & 15;
    const int r0 = tid >> 2;
    const int kc = tid & 3;

    for (int rt = blockIdx.y; rt * BM < cnt; rt += gridDim.y) {
        int m0 = rt * BM + r0, m1 = m0 + 64;
        int s0 = off + (m0 < cnt ? m0 : cnt - 1);
        int s1 = off + (m1 < cnt ? m1 : cnt - 1);
        const u16* a0 = hbuf + (size_t)s0 * F + kc * 8;
        const u16* a1 = hbuf + (size_t)s1 * F + kc * 8;
        const u16* b0 = w2t + ((size_t)e * H + nt * BN + r0) * F + kc * 8;
        const u16* b1 = b0 + (size_t)64 * F;

        f32x4 acc[4][4];
#pragma unroll
        for (int i = 0; i < 4; i++)
#pragma unroll
            for (int j = 0; j < 4; j++) acc[i][j] = (f32x4)0.f;

        for (int k0 = 0; k0 < F; k0 += BK) {
            __syncthreads();
            async_cp16(a0 + k0, &As[tid * 8]);
            async_cp16(a1 + k0, &As[(tid + 256) * 8]);
            async_cp16(b0 + k0, &Bs[tid * 8]);
            async_cp16(b1 + k0, &Bs[(tid + 256) * 8]);
            __syncthreads();

            bf16x8 af[4], bfv[4];
#pragma unroll
            for (int mi = 0; mi < 4; mi++)
                af[mi] = *(const bf16x8*)&As[(wr * 64 + mi * 16 + l16) * BK + quad * 8];
#pragma unroll
            for (int ni = 0; ni < 4; ni++)
                bfv[ni] = *(const bf16x8*)&Bs[(wc * 64 + ni * 16 + l16) * BK + quad * 8];
#pragma unroll
            for (int mi = 0; mi < 4; mi++)
#pragma unroll
                for (int ni = 0; ni < 4; ni++)
                    acc[mi][ni] = __builtin_amdgcn_mfma_f32_16x16x32_bf16(
                        af[mi], bfv[ni], acc[mi][ni], 0, 0, 0);
        }

#pragma unroll
        for (int mi = 0; mi < 4; mi++) {
#pragma unroll
            for (int r = 0; r < 4; r++) {
                int m = rt * BM + wr * 64 + mi * 16 + quad * 4 + r;
                if (m < cnt) {
                    int t = tokbuf[off + m];
                    float g = gwbuf[off + m];
                    size_t obase = (size_t)t * H;
#pragma unroll
                    for (int ni = 0; ni < 4; ni++) {
                        int col = nt * BN + wc * 64 + ni * 16 + l16;
                        atomicAdd(&out[obase + col], g * acc[mi][ni][r]);
                    }
                }
            }
        }
    }
}

// ---------- launch ----------
extern "C" void kernel_launch(void* const* d_in, const int* in_sizes, int n_in,
                              void* d_out, int out_size, void* d_ws, size_t ws_size,
                              hipStream_t stream) {
    const float* x    = (const float*)d_in[0];   // S,B,H fp32
    const float* gate = (const float*)d_in[1];   // T,K
    const int*   ce   = (const int*)d_in[2];     // T,K
    const float* w1   = (const float*)d_in[3];   // E,H,F
    const float* w2   = (const float*)d_in[4];   // E,F,H
    float* out = (float*)d_out;
    char* ws = (char*)d_ws;

    // workspace layout
    int*   counts  = (int*)(ws + 0);                 // 8
    int*   offsets = (int*)(ws + 64);                // 8
    int*   tokbuf  = (int*)(ws + 256);               // TK
    float* gwbuf   = (float*)(ws + 256 + TK * 4);    // TK
    size_t o = 256 + (size_t)TK * 8;
    u16* xb  = (u16*)(ws + o);  o += (size_t)T * H * 2;       // 16.8 MB
    u16* w1t = (u16*)(ws + o);  o += (size_t)E * F * H * 2;   // 67 MB  (E,F,H)
    u16* w2t = (u16*)(ws + o);  o += (size_t)E * H * F * 2;   // 67 MB  (E,H,F)
    u16* hbuf = (u16*)(ws + o);                                // TK x F bf16, 134 MB

    // ONE prep launch: transposes + cvt + routing + out-zeroing (no memsets)
    prep_kernel<<<dim3(64, 16, 18), 256, 0, stream>>>(
        x, w1, w2, gate, ce, xb, w1t, w2t, counts, offsets, tokbuf, gwbuf, out);

    fc1_kernel<<<dim3(F / BN, 32, E), 256, 0, stream>>>(xb, w1t, tokbuf, counts, offsets, hbuf);
    fc2_kernel<<<dim3(H / BN, 32, E), 256, 0, stream>>>(hbuf, w2t, tokbuf, gwbuf, counts, offsets, out);
}